// Round 9
// baseline (304.687 us; speedup 1.0000x reference)
//
#include <hip/hip_runtime.h>
#include <cstdint>
#include <cstddef>

typedef __bf16 bf16;
typedef __bf16 bf16x8 __attribute__((ext_vector_type(8)));
typedef __bf16 bf16x4 __attribute__((ext_vector_type(4)));
typedef float f32x4 __attribute__((ext_vector_type(4)));

#define LAMBDA_INIT_F 0.5560582041556405f
#define ONE_MINUS_LI_F 0.4439417958443595f

static constexpr int T = 2048;
static constexpr int ROWQ = 6144;  // q1|q2|k1|k2|v(2048)

__device__ __forceinline__ f32x4 mfma16(bf16x8 a, bf16x8 b, f32x4 c) {
  return __builtin_amdgcn_mfma_f32_16x16x32_bf16(a, b, c, 0, 0, 0);
}

__device__ __forceinline__ void gld16(const bf16* g, bf16* l) {
  __builtin_amdgcn_global_load_lds(
      (const __attribute__((address_space(1))) void*)g,
      (__attribute__((address_space(3))) void*)l, 16, 0, 0);
}

// ---------------- conversion kernels ----------------

__global__ void cvt_f32_bf16(const float* __restrict__ src, bf16* __restrict__ dst, int n4) {
  int i = blockIdx.x * blockDim.x + threadIdx.x;
  if (i < n4) {
    float4 v = reinterpret_cast<const float4*>(src)[i];
    bf16x4 o;
    o[0] = (bf16)v.x; o[1] = (bf16)v.y; o[2] = (bf16)v.z; o[3] = (bf16)v.w;
    reinterpret_cast<bf16x4*>(dst)[i] = o;
  }
}

// all weight transposes in ONE launch. [K][N] f32 -> [N][K] bf16
__global__ void transpose_all(const float* __restrict__ q1w, const float* __restrict__ q2w,
                              const float* __restrict__ k1w, const float* __restrict__ k2w,
                              const float* __restrict__ vw, const float* __restrict__ cw,
                              bf16* __restrict__ Wt, bf16* __restrict__ cwt) {
  __shared__ float t[32][33];
  const int id = blockIdx.x;
  const float* src;
  bf16* dst;
  int K, N, bx, by;
  if (id < 4096) {
    int wsel = id >> 10, r = id & 1023;
    src = (wsel == 0) ? q1w : (wsel == 1) ? q2w : (wsel == 2) ? k1w : k2w;
    dst = Wt + (size_t)wsel * 1024 * 1024;
    K = 1024; N = 1024; bx = r & 31; by = r >> 5;
  } else if (id < 6144) {
    int r = id - 4096;
    src = vw; dst = Wt + (size_t)4096 * 1024;
    K = 1024; N = 2048; bx = r & 63; by = r >> 6;
  } else {
    int r = id - 6144;
    src = cw; dst = cwt;
    K = 2048; N = 1024; bx = r & 31; by = r >> 5;
  }
  const int tx = threadIdx.x, ty = threadIdx.y;
  const int n0 = bx * 32, k0 = by * 32;
#pragma unroll
  for (int j = 0; j < 32; j += 8)
    t[ty + j][tx] = src[(size_t)(k0 + ty + j) * N + n0 + tx];
  __syncthreads();
#pragma unroll
  for (int j = 0; j < 32; j += 8)
    dst[(size_t)(n0 + ty + j) * K + k0 + tx] = (bf16)t[tx][ty + j];
}

// fallback: V part of qkv -> Vt[bh][d=128][t=2048]
__global__ void vtrans(const bf16* __restrict__ qkv, bf16* __restrict__ Vt) {
  __shared__ bf16 tile[64][72];
  const int tid = threadIdx.x;
  const int t0 = blockIdx.x * 64, dt = blockIdx.y, bh = blockIdx.z;
  const int b = bh >> 4, h = bh & 15;
#pragma unroll
  for (int i = 0; i < 2; ++i) {
    int S = tid + i * 256;
    int r = S >> 3, c = S & 7;
    *reinterpret_cast<bf16x8*>(&tile[r][c * 8]) =
        *reinterpret_cast<const bf16x8*>(
            &qkv[(size_t)(b * T + t0 + r) * ROWQ + 4096 + h * 128 + dt * 64 + c * 8]);
  }
  __syncthreads();
#pragma unroll
  for (int i = 0; i < 2; ++i) {
    int S = tid + i * 256;
    int dr = S >> 3, tc = S & 7;
    bf16x8 v;
#pragma unroll
    for (int j = 0; j < 8; ++j) v[j] = tile[tc * 8 + j][dr];
    *reinterpret_cast<bf16x8*>(
        &Vt[((size_t)bh * 128 + dt * 64 + dr) * 2048 + t0 + tc * 8]) = v;
  }
}

// ---------------- GEMM: A[M,K] x Bt[N,K] -> C[M,N], BK=64, dbuf, gload_lds ----------------
// proven sync skeleton: __syncthreads (full drain) at loop top, stage-early after it.
// FUSEV: blocks with bn>=4096 write their C tile transposed into Vt[bh][d][t].

template <typename OutT, int BM, bool FUSEV>
__global__ __launch_bounds__(256, BM == 128 ? 2 : 3) void gemm_bt(
    const bf16* __restrict__ A, const bf16* __restrict__ Bt, OutT* __restrict__ C,
    bf16* __restrict__ Vt, int M, int N, int K) {
  constexpr int AIT = BM / 32;            // A-staging granule iters
  constexpr int AN = (BM == 128) ? 4 : 2; // n-frags per wave
  constexpr int WCN = (BM == 128) ? 64 : 32;
  __shared__ __align__(16) bf16 smem[2 * BM * 64 + 2 * 128 * 64];
  const int tid = threadIdx.x;
  const int lane = tid & 63;
  const int wv = tid >> 6;
  const int wr = (BM == 128) ? (wv >> 1) : 0;
  const int wc = (BM == 128) ? (wv & 1) : wv;
  const int bm = blockIdx.y * BM, bn = blockIdx.x * 128;
  const int lr = lane & 15, lg = lane >> 4;

  f32x4 acc[4][AN] = {};
  const int KT = K >> 6;

#define ASB(buf) (smem + (buf) * (BM * 64))
#define BSB(buf) (smem + 2 * BM * 64 + (buf) * (128 * 64))

#define STAGE_AB(buf, kk0)                                                      \
  do {                                                                          \
    _Pragma("unroll") for (int i_ = 0; i_ < 4; ++i_) {                          \
      int S_ = (i_ * 4 + wv) * 64 + lane;                                       \
      int rw_ = S_ >> 3;                                                        \
      int cg_ = (S_ & 7) ^ (rw_ & 7);                                           \
      if (i_ < AIT)                                                             \
        gld16(&A[(size_t)(bm + rw_) * K + (kk0) + cg_ * 8], ASB(buf) + (i_ * 4 + wv) * 512); \
      gld16(&Bt[(size_t)(bn + rw_) * K + (kk0) + cg_ * 8], BSB(buf) + (i_ * 4 + wv) * 512); \
    }                                                                           \
  } while (0)

  STAGE_AB(0, 0);
  for (int kt = 0; kt < KT; ++kt) {
    const int cur = kt & 1;
    __syncthreads();  // full drain: all waves' tile-kt loads landed; buffers released
    if (kt + 1 < KT) STAGE_AB(cur ^ 1, (kt + 1) * 64);
#pragma unroll
    for (int kh = 0; kh < 2; ++kh) {
      bf16x8 af[4], bfr[AN];
#pragma unroll
      for (int m = 0; m < 4; ++m)
        af[m] = *reinterpret_cast<const bf16x8*>(
            ASB(cur) + (wr * 64 + m * 16 + lr) * 64 + (((kh * 4 + lg) ^ (lr & 7)) * 8));
#pragma unroll
      for (int n = 0; n < AN; ++n)
        bfr[n] = *reinterpret_cast<const bf16x8*>(
            BSB(cur) + (wc * WCN + n * 16 + lr) * 64 + (((kh * 4 + lg) ^ (lr & 7)) * 8));
#pragma unroll
      for (int m = 0; m < 4; ++m)
#pragma unroll
        for (int n = 0; n < AN; ++n)
          acc[m][n] = mfma16(af[m], bfr[n], acc[m][n]);
    }
  }
#undef STAGE_AB
#undef ASB
#undef BSB

  bool vpath = false;
  if constexpr (FUSEV) vpath = (bn >= 4096);
  if (!vpath) {
#pragma unroll
    for (int m = 0; m < 4; ++m)
#pragma unroll
      for (int n = 0; n < AN; ++n)
#pragma unroll
        for (int r = 0; r < 4; ++r) {
          int row = bm + wr * 64 + m * 16 + lg * 4 + r;
          int col = bn + wc * WCN + n * 16 + lr;
          C[(size_t)row * N + col] = (OutT)acc[m][n][r];
        }
  } else if constexpr (FUSEV) {
    // transpose C tile (rows=t, cols=d) into Vt[bh][d][t] via LDS
    constexpr int LDT = 136;  // bf16; 272B row stride, 16B aligned
    bf16* tb = smem;          // 128*136*2 = 34816 B, fits
    __syncthreads();
#pragma unroll
    for (int m = 0; m < 4; ++m)
#pragma unroll
      for (int n = 0; n < AN; ++n) {
        int dl = wc * WCN + n * 16 + lr;
        int tl = wr * 64 + m * 16 + lg * 4;
        bf16x4 p;
#pragma unroll
        for (int r = 0; r < 4; ++r) p[r] = (bf16)acc[m][n][r];
        *reinterpret_cast<bf16x4*>(&tb[dl * LDT + tl]) = p;
      }
    __syncthreads();
    const int b_ = bm >> 11;
    const int t0g = bm & 2047;
    const int h_ = (bn - 4096) >> 7;
#pragma unroll
    for (int i = 0; i < 8; ++i) {
      int S = i * 256 + tid;
      int dl = S >> 4, tc = S & 15;
      bf16x8 v = *reinterpret_cast<const bf16x8*>(&tb[dl * LDT + tc * 8]);
      *reinterpret_cast<bf16x8*>(
          &Vt[(((size_t)b_ * 16 + h_) * 128 + dl) * 2048 + t0g + tc * 8]) = v;
    }
  }
}

// ---------------- differential flash attention + per-head LayerNorm ----------------
// round-2-proven dataflow: forward QK^T (A=Q,B=K), P via per-wave LDS strip.

__device__ __forceinline__ void att_step(
    const bf16* __restrict__ K1c, const bf16* __restrict__ K2c,
    const bf16* __restrict__ Vc, bf16* __restrict__ Pw,
    const bf16x8 (&q1f)[2], const bf16x8 (&q2f)[2],
    f32x4 (&o1)[8], f32x4 (&o2)[8], f32x4& l1, f32x4& l2,
    bool edge, int lr, int lg, int wv, const bf16x8& onesf) {
  constexpr int LDP = 72;
  f32x4 s1[4] = {}, s2[4] = {};
#pragma unroll
  for (int n = 0; n < 4; ++n) {
    int krow = n * 16 + lr;
#pragma unroll
    for (int kc = 0; kc < 2; ++kc) {
      int off = krow * 64 + (((kc * 4 + lg) ^ (lr & 7)) * 8);
      bf16x8 kf1 = *reinterpret_cast<const bf16x8*>(&K1c[off]);
      bf16x8 kf2 = *reinterpret_cast<const bf16x8*>(&K2c[off]);
      s1[n] = mfma16(q1f[kc], kf1, s1[n]);  // S: row=q, col=k
      s2[n] = mfma16(q2f[kc], kf2, s2[n]);
    }
  }
  // lane (lg,lr) holds S[q = lg*4+r][k = n*16+lr]
#pragma unroll
  for (int n = 0; n < 4; ++n)
#pragma unroll
    for (int r = 0; r < 4; ++r) {
      float e1 = fmaf(s1[n][r], 0.125f, -16.0f);
      float e2 = fmaf(s2[n][r], 0.125f, -16.0f);
      if (edge) {
        int qq = wv * 16 + lg * 4 + r;
        int kk = n * 16 + lr;
        if (kk > qq) { e1 = -10000.f; e2 = -10000.f; }
      }
      s1[n][r] = __expf(e1);
      s2[n][r] = __expf(e2);
    }
  bf16x8 pa1[2], pa2[2];
#pragma unroll
  for (int n = 0; n < 4; ++n)
#pragma unroll
    for (int r = 0; r < 4; ++r)
      Pw[(lg * 4 + r) * LDP + n * 16 + lr] = (bf16)s1[n][r];
#pragma unroll
  for (int kc = 0; kc < 2; ++kc)
    pa1[kc] = *reinterpret_cast<const bf16x8*>(&Pw[lr * LDP + kc * 32 + lg * 8]);
#pragma unroll
  for (int n = 0; n < 4; ++n)
#pragma unroll
    for (int r = 0; r < 4; ++r)
      Pw[(lg * 4 + r) * LDP + n * 16 + lr] = (bf16)s2[n][r];
#pragma unroll
  for (int kc = 0; kc < 2; ++kc)
    pa2[kc] = *reinterpret_cast<const bf16x8*>(&Pw[lr * LDP + kc * 32 + lg * 8]);
#pragma unroll
  for (int kc = 0; kc < 2; ++kc) {
    l1 = mfma16(pa1[kc], onesf, l1);
    l2 = mfma16(pa2[kc], onesf, l2);
#pragma unroll
    for (int nf = 0; nf < 8; ++nf) {
      int dd = nf * 16 + lr;
      int off = dd * 64 + (((kc * 4 + lg) ^ (lr & 7)) * 8);
      bf16x8 vb = *reinterpret_cast<const bf16x8*>(&Vc[off]);
      o1[nf] = mfma16(pa1[kc], vb, o1[nf]);
      o2[nf] = mfma16(pa2[kc], vb, o2[nf]);
    }
  }
}

__global__ __launch_bounds__(256, 2) void diff_attn(const bf16* __restrict__ qkv,
                                                    const bf16* __restrict__ Vtg,
                                                    const float* __restrict__ lq1,
                                                    const float* __restrict__ lk1,
                                                    const float* __restrict__ lq2,
                                                    const float* __restrict__ lk2,
                                                    bf16* __restrict__ yln) {
  constexpr int LDP = 72;
  __shared__ __align__(16) bf16 K1s[2][64 * 64];
  __shared__ __align__(16) bf16 K2s[2][64 * 64];
  __shared__ __align__(16) bf16 Vs[2][128 * 64];
  __shared__ __align__(16) bf16 Ps[4][16 * LDP];

  const int x = blockIdx.x;
  const int bh = blockIdx.y;
  const int b = bh >> 4, h = bh & 15;
  const int tid = threadIdx.x, lane = tid & 63, wv = tid >> 6;
  const int lr = lane & 15, lg = lane >> 4;
  const int u = b ? x : 15 - x;
  const int qtA = 31 - u;  // big tile
  const int qtB = u;       // small tile

  const int q1c = h * 64;
  const int q2c = 1024 + h * 64;
  const int k1c = 2048 + h * 64;
  const int k2c = 3072 + h * 64;

  // lambda
  float a1 = lq1[h * 64 + lane] * lk1[h * 64 + lane];
  float a2 = lq2[h * 64 + lane] * lk2[h * 64 + lane];
#pragma unroll
  for (int m = 32; m >= 1; m >>= 1) {
    a1 += __shfl_xor(a1, m);
    a2 += __shfl_xor(a2, m);
  }
  const float lam = __expf(a1) - __expf(a2) + LAMBDA_INIT_F;

  bf16x8 onesf;
#pragma unroll
  for (int j = 0; j < 8; ++j) onesf[j] = (bf16)1.0f;

  // Q fragments for both tiles (A-operand)
  bf16x8 q1fA[2], q2fA[2], q1fB[2], q2fB[2];
  {
    const bf16* qa = qkv + (size_t)(b * T + qtA * 64 + wv * 16 + lr) * ROWQ;
    const bf16* qb = qkv + (size_t)(b * T + qtB * 64 + wv * 16 + lr) * ROWQ;
#pragma unroll
    for (int kc = 0; kc < 2; ++kc) {
      q1fA[kc] = *reinterpret_cast<const bf16x8*>(qa + q1c + kc * 32 + lg * 8);
      q2fA[kc] = *reinterpret_cast<const bf16x8*>(qa + q2c + kc * 32 + lg * 8);
      q1fB[kc] = *reinterpret_cast<const bf16x8*>(qb + q1c + kc * 32 + lg * 8);
      q2fB[kc] = *reinterpret_cast<const bf16x8*>(qb + q2c + kc * 32 + lg * 8);
    }
  }

  f32x4 o1A[8] = {}, o2A[8] = {}, o1B[8] = {}, o2B[8] = {};
  f32x4 lA1 = {}, lA2 = {}, lB1 = {}, lB2 = {};

#define STAGE_KV(buf, tt0)                                                       \
  do {                                                                           \
    const bf16* kb_ = qkv + (size_t)(b * T + (tt0)) * ROWQ;                      \
    _Pragma("unroll") for (int i_ = 0; i_ < 2; ++i_) {                           \
      int S_ = (i_ * 4 + wv) * 64 + lane;                                        \
      int rw_ = S_ >> 3;                                                         \
      int cg_ = (S_ & 7) ^ (rw_ & 7);                                            \
      gld16(kb_ + (size_t)rw_ * ROWQ + k1c + cg_ * 8, &K1s[buf][(i_ * 4 + wv) * 512]); \
      gld16(kb_ + (size_t)rw_ * ROWQ + k2c + cg_ * 8, &K2s[buf][(i_ * 4 + wv) * 512]); \
    }                                                                            \
    _Pragma("unroll") for (int i_ = 0; i_ < 4; ++i_) {                           \
      int S_ = (i_ * 4 + wv) * 64 + lane;                                        \
      int dd_ = S_ >> 3;                                                         \
      int cg_ = (S_ & 7) ^ (dd_ & 7);                                            \
      gld16(Vtg + ((size_t)bh * 128 + dd_) * 2048 + (tt0) + cg_ * 8,             \
            &Vs[buf][(i_ * 4 + wv) * 512]);                                      \
    }                                                                            \
  } while (0)

  STAGE_KV(0, 0);
  for (int kt = 0; kt <= qtA; ++kt) {
    const int cur = kt & 1;
    __syncthreads();  // full drain + barrier: tile-kt loads landed on all waves
    if (kt < qtA) STAGE_KV(cur ^ 1, (kt + 1) * 64);
    att_step(&K1s[cur][0], &K2s[cur][0], &Vs[cur][0], &Ps[wv][0], q1fA, q2fA,
             o1A, o2A, lA1, lA2, kt == qtA, lr, lg, wv, onesf);
    if (kt <= qtB)
      att_step(&K1s[cur][0], &K2s[cur][0], &Vs[cur][0], &Ps[wv][0], q1fB, q2fB,
               o1B, o2B, lB1, lB2, kt == qtB, lr, lg, wv, onesf);
  }
#undef STAGE_KV

#define ATT_EPI(o1_, o2_, l1_, l2_, qt_)                                         \
  do {                                                                           \
    float sum_[4] = {}, sq_[4] = {};                                             \
    float i1_[4], i2_[4];                                                        \
    _Pragma("unroll") for (int r_ = 0; r_ < 4; ++r_) {                           \
      i1_[r_] = 1.f / l1_[r_];                                                   \
      i2_[r_] = lam / l2_[r_];                                                   \
    }                                                                            \
    _Pragma("unroll") for (int nf_ = 0; nf_ < 8; ++nf_)                          \
    _Pragma("unroll") for (int r_ = 0; r_ < 4; ++r_) {                           \
      float v_ = o1_[nf_][r_] * i1_[r_] - o2_[nf_][r_] * i2_[r_];                \
      o1_[nf_][r_] = v_;                                                         \
      sum_[r_] += v_;                                                            \
      sq_[r_] += v_ * v_;                                                        \
    }                                                                            \
    _Pragma("unroll") for (int r_ = 0; r_ < 4; ++r_)                             \
    _Pragma("unroll") for (int mm_ = 8; mm_ >= 1; mm_ >>= 1) {                   \
      sum_[r_] += __shfl_xor(sum_[r_], mm_);                                     \
      sq_[r_] += __shfl_xor(sq_[r_], mm_);                                       \
    }                                                                            \
    _Pragma("unroll") for (int r_ = 0; r_ < 4; ++r_) {                           \
      float mu_ = sum_[r_] * (1.f / 128.f);                                      \
      float var_ = sq_[r_] * (1.f / 128.f) - mu_ * mu_;                          \
      float rs_ = rsqrtf(var_ + 1e-5f) * ONE_MINUS_LI_F;                         \
      int row_ = b * T + (qt_)*64 + wv * 16 + lg * 4 + r_;                       \
      bf16* orow_ = yln + (size_t)row_ * 2048 + h * 128;                         \
      _Pragma("unroll") for (int nf_ = 0; nf_ < 8; ++nf_)                        \
          orow_[nf_ * 16 + lr] = (bf16)((o1_[nf_][r_] - mu_) * rs_);             \
    }                                                                            \
  } while (0)

  ATT_EPI(o1A, o2A, lA1, lA2, qtA);
  ATT_EPI(o1B, o2B, lB1, lB2, qtB);
#undef ATT_EPI
}

// ---------------- launch ----------------

extern "C" void kernel_launch(void* const* d_in, const int* in_sizes, int n_in,
                              void* d_out, int out_size, void* d_ws, size_t ws_size,
                              hipStream_t stream) {
  const float* x   = (const float*)d_in[0];
  const float* q1w = (const float*)d_in[1];
  const float* q2w = (const float*)d_in[2];
  const float* k1w = (const float*)d_in[3];
  const float* k2w = (const float*)d_in[4];
  const float* vw  = (const float*)d_in[5];
  const float* cw  = (const float*)d_in[6];
  const float* lq1 = (const float*)d_in[7];
  const float* lk1 = (const float*)d_in[8];
  const float* lq2 = (const float*)d_in[9];
  const float* lk2 = (const float*)d_in[10];
  float* out = (float*)d_out;

  char* ws = (char*)d_ws;
  bf16* qkv = (bf16*)(ws);                 // 50331648 B
  bf16* Wt  = (bf16*)(ws + 50331648);      // 12582912 B (dead after gemm1)
  bf16* xb  = (bf16*)(ws + 62914560);      // 8388608 B  (dead after gemm1)
  bf16* cwt = (bf16*)(ws + 71303168);      // 4194304 B
  bf16* yln = (bf16*)(ws + 75497472);      // 16777216 B

  const bool fuse_v = (ws_size >= 92274688ull + 16777216ull);
  // fused: Vt after yln (needs 109 MB ws); fallback: Vt overlaps Wt+xb (dead only
  // after gemm1, so fallback uses the separate vtrans kernel)
  bf16* Vt = fuse_v ? (bf16*)(ws + 92274688) : (bf16*)(ws + 50331648);

  cvt_f32_bf16<<<4096, 256, 0, stream>>>(x, xb, 4096 * 1024 / 4);

  transpose_all<<<8192, dim3(32, 8), 0, stream>>>(q1w, q2w, k1w, k2w, vw, cw, Wt, cwt);

  // qkv = x @ [q1|q2|k1|k2|v]; V-part transposed straight into Vt when fused
  if (fuse_v) {
    gemm_bt<bf16, 128, true><<<dim3(48, 32), 256, 0, stream>>>(xb, Wt, qkv, Vt, 4096, 6144, 1024);
  } else {
    gemm_bt<bf16, 128, false><<<dim3(48, 32), 256, 0, stream>>>(xb, Wt, qkv, nullptr, 4096, 6144, 1024);
    vtrans<<<dim3(32, 2, 32), 256, 0, stream>>>(qkv, Vt);
  }

  // differential attention + per-head LN
  diff_attn<<<dim3(16, 32), 256, 0, stream>>>(qkv, Vt, lq1, lk1, lq2, lk2, yln);

  // out = yln @ c_w
  gemm_bt<float, 64, false><<<dim3(8, 64), 256, 0, stream>>>(yln, cwt, out, nullptr, 4096, 1024, 2048);
}

// Round 10
// 288.783 us; speedup vs baseline: 1.0551x; 1.0551x over previous
//
#include <hip/hip_runtime.h>
#include <cstdint>
#include <cstddef>

typedef __bf16 bf16;
typedef __bf16 bf16x8 __attribute__((ext_vector_type(8)));
typedef __bf16 bf16x4 __attribute__((ext_vector_type(4)));
typedef float f32x4 __attribute__((ext_vector_type(4)));

#define LAMBDA_INIT_F 0.5560582041556405f
#define ONE_MINUS_LI_F 0.4439417958443595f

static constexpr int T = 2048;
static constexpr int ROWQ = 6144;  // q1|q2|k1|k2|v(2048)

__device__ __forceinline__ f32x4 mfma16(bf16x8 a, bf16x8 b, f32x4 c) {
  return __builtin_amdgcn_mfma_f32_16x16x32_bf16(a, b, c, 0, 0, 0);
}

__device__ __forceinline__ void gld16(const bf16* g, bf16* l) {
  __builtin_amdgcn_global_load_lds(
      (const __attribute__((address_space(1))) void*)g,
      (__attribute__((address_space(3))) void*)l, 16, 0, 0);
}

// ---------------- conversion kernels ----------------

__global__ void cvt_f32_bf16(const float* __restrict__ src, bf16* __restrict__ dst, int n4) {
  int i = blockIdx.x * blockDim.x + threadIdx.x;
  if (i < n4) {
    float4 v = reinterpret_cast<const float4*>(src)[i];
    bf16x4 o;
    o[0] = (bf16)v.x; o[1] = (bf16)v.y; o[2] = (bf16)v.z; o[3] = (bf16)v.w;
    reinterpret_cast<bf16x4*>(dst)[i] = o;
  }
}

// all weight transposes in ONE launch. [K][N] f32 -> [N][K] bf16
__global__ void transpose_all(const float* __restrict__ q1w, const float* __restrict__ q2w,
                              const float* __restrict__ k1w, const float* __restrict__ k2w,
                              const float* __restrict__ vw, const float* __restrict__ cw,
                              bf16* __restrict__ Wt, bf16* __restrict__ cwt) {
  __shared__ float t[32][33];
  const int id = blockIdx.x;
  const float* src;
  bf16* dst;
  int K, N, bx, by;
  if (id < 4096) {
    int wsel = id >> 10, r = id & 1023;
    src = (wsel == 0) ? q1w : (wsel == 1) ? q2w : (wsel == 2) ? k1w : k2w;
    dst = Wt + (size_t)wsel * 1024 * 1024;
    K = 1024; N = 1024; bx = r & 31; by = r >> 5;
  } else if (id < 6144) {
    int r = id - 4096;
    src = vw; dst = Wt + (size_t)4096 * 1024;
    K = 1024; N = 2048; bx = r & 63; by = r >> 6;
  } else {
    int r = id - 6144;
    src = cw; dst = cwt;
    K = 2048; N = 1024; bx = r & 31; by = r >> 5;
  }
  const int tx = threadIdx.x, ty = threadIdx.y;
  const int n0 = bx * 32, k0 = by * 32;
#pragma unroll
  for (int j = 0; j < 32; j += 8)
    t[ty + j][tx] = src[(size_t)(k0 + ty + j) * N + n0 + tx];
  __syncthreads();
#pragma unroll
  for (int j = 0; j < 32; j += 8)
    dst[(size_t)(n0 + ty + j) * K + k0 + tx] = (bf16)t[tx][ty + j];
}

// fallback: V part of qkv -> Vt[bh][d=128][t=2048]
__global__ void vtrans(const bf16* __restrict__ qkv, bf16* __restrict__ Vt) {
  __shared__ bf16 tile[64][72];
  const int tid = threadIdx.x;
  const int t0 = blockIdx.x * 64, dt = blockIdx.y, bh = blockIdx.z;
  const int b = bh >> 4, h = bh & 15;
#pragma unroll
  for (int i = 0; i < 2; ++i) {
    int S = tid + i * 256;
    int r = S >> 3, c = S & 7;
    *reinterpret_cast<bf16x8*>(&tile[r][c * 8]) =
        *reinterpret_cast<const bf16x8*>(
            &qkv[(size_t)(b * T + t0 + r) * ROWQ + 4096 + h * 128 + dt * 64 + c * 8]);
  }
  __syncthreads();
#pragma unroll
  for (int i = 0; i < 2; ++i) {
    int S = tid + i * 256;
    int dr = S >> 3, tc = S & 7;
    bf16x8 v;
#pragma unroll
    for (int j = 0; j < 8; ++j) v[j] = tile[tc * 8 + j][dr];
    *reinterpret_cast<bf16x8*>(
        &Vt[((size_t)bh * 128 + dt * 64 + dr) * 2048 + t0 + tc * 8]) = v;
  }
}

// ---------------- GEMM: A[M,K] x Bt[N,K] -> C[M,N], BK=64, dbuf, gload_lds ----------------
// proven sync skeleton: __syncthreads (full drain) at loop top, stage-early after it.
// FUSEV: blocks with bn>=4096 write their C tile transposed into Vt[bh][d][t].

template <typename OutT, int BM, bool FUSEV>
__global__ __launch_bounds__(256, BM == 128 ? 2 : 3) void gemm_bt(
    const bf16* __restrict__ A, const bf16* __restrict__ Bt, OutT* __restrict__ C,
    bf16* __restrict__ Vt, int M, int N, int K) {
  constexpr int AIT = BM / 32;            // A-staging granule iters
  constexpr int AN = (BM == 128) ? 4 : 2; // n-frags per wave
  constexpr int WCN = (BM == 128) ? 64 : 32;
  __shared__ __align__(16) bf16 smem[2 * BM * 64 + 2 * 128 * 64];
  const int tid = threadIdx.x;
  const int lane = tid & 63;
  const int wv = tid >> 6;
  const int wr = (BM == 128) ? (wv >> 1) : 0;
  const int wc = (BM == 128) ? (wv & 1) : wv;
  const int bm = blockIdx.y * BM, bn = blockIdx.x * 128;
  const int lr = lane & 15, lg = lane >> 4;

  f32x4 acc[4][AN] = {};
  const int KT = K >> 6;

#define ASB(buf) (smem + (buf) * (BM * 64))
#define BSB(buf) (smem + 2 * BM * 64 + (buf) * (128 * 64))

#define STAGE_AB(buf, kk0)                                                      \
  do {                                                                          \
    _Pragma("unroll") for (int i_ = 0; i_ < 4; ++i_) {                          \
      int S_ = (i_ * 4 + wv) * 64 + lane;                                       \
      int rw_ = S_ >> 3;                                                        \
      int cg_ = (S_ & 7) ^ (rw_ & 7);                                           \
      if (i_ < AIT)                                                             \
        gld16(&A[(size_t)(bm + rw_) * K + (kk0) + cg_ * 8], ASB(buf) + (i_ * 4 + wv) * 512); \
      gld16(&Bt[(size_t)(bn + rw_) * K + (kk0) + cg_ * 8], BSB(buf) + (i_ * 4 + wv) * 512); \
    }                                                                           \
  } while (0)

  STAGE_AB(0, 0);
  for (int kt = 0; kt < KT; ++kt) {
    const int cur = kt & 1;
    __syncthreads();  // full drain: all waves' tile-kt loads landed; buffers released
    if (kt + 1 < KT) STAGE_AB(cur ^ 1, (kt + 1) * 64);
#pragma unroll
    for (int kh = 0; kh < 2; ++kh) {
      bf16x8 af[4], bfr[AN];
#pragma unroll
      for (int m = 0; m < 4; ++m)
        af[m] = *reinterpret_cast<const bf16x8*>(
            ASB(cur) + (wr * 64 + m * 16 + lr) * 64 + (((kh * 4 + lg) ^ (lr & 7)) * 8));
#pragma unroll
      for (int n = 0; n < AN; ++n)
        bfr[n] = *reinterpret_cast<const bf16x8*>(
            BSB(cur) + (wc * WCN + n * 16 + lr) * 64 + (((kh * 4 + lg) ^ (lr & 7)) * 8));
#pragma unroll
      for (int m = 0; m < 4; ++m)
#pragma unroll
        for (int n = 0; n < AN; ++n)
          acc[m][n] = mfma16(af[m], bfr[n], acc[m][n]);
    }
  }
#undef STAGE_AB
#undef ASB
#undef BSB

  bool vpath = false;
  if constexpr (FUSEV) vpath = (bn >= 4096);
  if (!vpath) {
#pragma unroll
    for (int m = 0; m < 4; ++m)
#pragma unroll
      for (int n = 0; n < AN; ++n)
#pragma unroll
        for (int r = 0; r < 4; ++r) {
          int row = bm + wr * 64 + m * 16 + lg * 4 + r;
          int col = bn + wc * WCN + n * 16 + lr;
          C[(size_t)row * N + col] = (OutT)acc[m][n][r];
        }
  } else if constexpr (FUSEV) {
    // transpose C tile (rows=t, cols=d) into Vt[bh][d][t] via LDS
    constexpr int LDT = 136;  // bf16; 272B row stride, 16B aligned
    bf16* tb = smem;          // 128*136*2 = 34816 B, fits
    __syncthreads();
#pragma unroll
    for (int m = 0; m < 4; ++m)
#pragma unroll
      for (int n = 0; n < AN; ++n) {
        int dl = wc * WCN + n * 16 + lr;
        int tl = wr * 64 + m * 16 + lg * 4;
        bf16x4 p;
#pragma unroll
        for (int r = 0; r < 4; ++r) p[r] = (bf16)acc[m][n][r];
        *reinterpret_cast<bf16x4*>(&tb[dl * LDT + tl]) = p;
      }
    __syncthreads();
    const int b_ = bm >> 11;
    const int t0g = bm & 2047;
    const int h_ = (bn - 4096) >> 7;
#pragma unroll
    for (int i = 0; i < 8; ++i) {
      int S = i * 256 + tid;
      int dl = S >> 4, tc = S & 15;
      bf16x8 v = *reinterpret_cast<const bf16x8*>(&tb[dl * LDT + tc * 8]);
      *reinterpret_cast<bf16x8*>(
          &Vt[(((size_t)b_ * 16 + h_) * 128 + dl) * 2048 + t0g + tc * 8]) = v;
    }
  }
}

// ---------------- differential flash attention + per-head LayerNorm ----------------
// round-2-proven dataflow: forward QK^T (A=Q,B=K), P via per-wave LDS strip.
// XCD-locality swizzle: all 16 q-tile blocks of one head land on one XCD (bid%8).

__device__ __forceinline__ void att_step(
    const bf16* __restrict__ K1c, const bf16* __restrict__ K2c,
    const bf16* __restrict__ Vc, bf16* __restrict__ Pw,
    const bf16x8 (&q1f)[2], const bf16x8 (&q2f)[2],
    f32x4 (&o1)[8], f32x4 (&o2)[8], f32x4& l1, f32x4& l2,
    bool edge, int lr, int lg, int wv, const bf16x8& onesf) {
  constexpr int LDP = 72;
  f32x4 s1[4] = {}, s2[4] = {};
#pragma unroll
  for (int n = 0; n < 4; ++n) {
    int krow = n * 16 + lr;
#pragma unroll
    for (int kc = 0; kc < 2; ++kc) {
      int off = krow * 64 + (((kc * 4 + lg) ^ (lr & 7)) * 8);
      bf16x8 kf1 = *reinterpret_cast<const bf16x8*>(&K1c[off]);
      bf16x8 kf2 = *reinterpret_cast<const bf16x8*>(&K2c[off]);
      s1[n] = mfma16(q1f[kc], kf1, s1[n]);  // S: row=q, col=k
      s2[n] = mfma16(q2f[kc], kf2, s2[n]);
    }
  }
  // lane (lg,lr) holds S[q = lg*4+r][k = n*16+lr]
#pragma unroll
  for (int n = 0; n < 4; ++n)
#pragma unroll
    for (int r = 0; r < 4; ++r) {
      float e1 = fmaf(s1[n][r], 0.125f, -16.0f);
      float e2 = fmaf(s2[n][r], 0.125f, -16.0f);
      if (edge) {
        int qq = wv * 16 + lg * 4 + r;
        int kk = n * 16 + lr;
        if (kk > qq) { e1 = -10000.f; e2 = -10000.f; }
      }
      s1[n][r] = __expf(e1);
      s2[n][r] = __expf(e2);
    }
  bf16x8 pa1[2], pa2[2];
#pragma unroll
  for (int n = 0; n < 4; ++n)
#pragma unroll
    for (int r = 0; r < 4; ++r)
      Pw[(lg * 4 + r) * LDP + n * 16 + lr] = (bf16)s1[n][r];
#pragma unroll
  for (int kc = 0; kc < 2; ++kc)
    pa1[kc] = *reinterpret_cast<const bf16x8*>(&Pw[lr * LDP + kc * 32 + lg * 8]);
#pragma unroll
  for (int n = 0; n < 4; ++n)
#pragma unroll
    for (int r = 0; r < 4; ++r)
      Pw[(lg * 4 + r) * LDP + n * 16 + lr] = (bf16)s2[n][r];
#pragma unroll
  for (int kc = 0; kc < 2; ++kc)
    pa2[kc] = *reinterpret_cast<const bf16x8*>(&Pw[lr * LDP + kc * 32 + lg * 8]);
#pragma unroll
  for (int kc = 0; kc < 2; ++kc) {
    l1 = mfma16(pa1[kc], onesf, l1);
    l2 = mfma16(pa2[kc], onesf, l2);
#pragma unroll
    for (int nf = 0; nf < 8; ++nf) {
      int dd = nf * 16 + lr;
      int off = dd * 64 + (((kc * 4 + lg) ^ (lr & 7)) * 8);
      bf16x8 vb = *reinterpret_cast<const bf16x8*>(&Vc[off]);
      o1[nf] = mfma16(pa1[kc], vb, o1[nf]);
      o2[nf] = mfma16(pa2[kc], vb, o2[nf]);
    }
  }
}

__global__ __launch_bounds__(256, 2) void diff_attn(const bf16* __restrict__ qkv,
                                                    const bf16* __restrict__ Vtg,
                                                    const float* __restrict__ lq1,
                                                    const float* __restrict__ lk1,
                                                    const float* __restrict__ lq2,
                                                    const float* __restrict__ lk2,
                                                    bf16* __restrict__ yln) {
  constexpr int LDP = 72;
  __shared__ __align__(16) bf16 K1s[2][64 * 64];
  __shared__ __align__(16) bf16 K2s[2][64 * 64];
  __shared__ __align__(16) bf16 Vs[2][128 * 64];
  __shared__ __align__(16) bf16 Ps[4][16 * LDP];

  // XCD-locality decode: bid = (bh&7) + 8*((bh>>3) + 4*x)  (bijective over 512)
  const int bid = blockIdx.x;
  const int r8 = bid & 7;
  const int g = bid >> 3;          // 0..63
  const int qh = g & 3;            // bh high bits
  const int x = g >> 2;            // 0..15
  const int bh = r8 + 8 * qh;
  const int b = bh >> 4, h = bh & 15;
  const int tid = threadIdx.x, lane = tid & 63, wv = tid >> 6;
  const int lr = lane & 15, lg = lane >> 4;
  const int u = x;
  const int qtA = 31 - u;  // big tile
  const int qtB = u;       // small tile

  const int q1c = h * 64;
  const int q2c = 1024 + h * 64;
  const int k1c = 2048 + h * 64;
  const int k2c = 3072 + h * 64;

  // lambda
  float a1 = lq1[h * 64 + lane] * lk1[h * 64 + lane];
  float a2 = lq2[h * 64 + lane] * lk2[h * 64 + lane];
#pragma unroll
  for (int m = 32; m >= 1; m >>= 1) {
    a1 += __shfl_xor(a1, m);
    a2 += __shfl_xor(a2, m);
  }
  const float lam = __expf(a1) - __expf(a2) + LAMBDA_INIT_F;

  bf16x8 onesf;
#pragma unroll
  for (int j = 0; j < 8; ++j) onesf[j] = (bf16)1.0f;

  // Q fragments for both tiles (A-operand)
  bf16x8 q1fA[2], q2fA[2], q1fB[2], q2fB[2];
  {
    const bf16* qa = qkv + (size_t)(b * T + qtA * 64 + wv * 16 + lr) * ROWQ;
    const bf16* qb = qkv + (size_t)(b * T + qtB * 64 + wv * 16 + lr) * ROWQ;
#pragma unroll
    for (int kc = 0; kc < 2; ++kc) {
      q1fA[kc] = *reinterpret_cast<const bf16x8*>(qa + q1c + kc * 32 + lg * 8);
      q2fA[kc] = *reinterpret_cast<const bf16x8*>(qa + q2c + kc * 32 + lg * 8);
      q1fB[kc] = *reinterpret_cast<const bf16x8*>(qb + q1c + kc * 32 + lg * 8);
      q2fB[kc] = *reinterpret_cast<const bf16x8*>(qb + q2c + kc * 32 + lg * 8);
    }
  }

  f32x4 o1A[8] = {}, o2A[8] = {}, o1B[8] = {}, o2B[8] = {};
  f32x4 lA1 = {}, lA2 = {}, lB1 = {}, lB2 = {};

#define STAGE_KV(buf, tt0)                                                       \
  do {                                                                           \
    const bf16* kb_ = qkv + (size_t)(b * T + (tt0)) * ROWQ;                      \
    _Pragma("unroll") for (int i_ = 0; i_ < 2; ++i_) {                           \
      int S_ = (i_ * 4 + wv) * 64 + lane;                                        \
      int rw_ = S_ >> 3;                                                         \
      int cg_ = (S_ & 7) ^ (rw_ & 7);                                            \
      gld16(kb_ + (size_t)rw_ * ROWQ + k1c + cg_ * 8, &K1s[buf][(i_ * 4 + wv) * 512]); \
      gld16(kb_ + (size_t)rw_ * ROWQ + k2c + cg_ * 8, &K2s[buf][(i_ * 4 + wv) * 512]); \
    }                                                                            \
    _Pragma("unroll") for (int i_ = 0; i_ < 4; ++i_) {                           \
      int S_ = (i_ * 4 + wv) * 64 + lane;                                        \
      int dd_ = S_ >> 3;                                                         \
      int cg_ = (S_ & 7) ^ (dd_ & 7);                                            \
      gld16(Vtg + ((size_t)bh * 128 + dd_) * 2048 + (tt0) + cg_ * 8,             \
            &Vs[buf][(i_ * 4 + wv) * 512]);                                      \
    }                                                                            \
  } while (0)

  STAGE_KV(0, 0);
  for (int kt = 0; kt <= qtA; ++kt) {
    const int cur = kt & 1;
    __syncthreads();  // full drain + barrier: tile-kt loads landed on all waves
    if (kt < qtA) STAGE_KV(cur ^ 1, (kt + 1) * 64);
    att_step(&K1s[cur][0], &K2s[cur][0], &Vs[cur][0], &Ps[wv][0], q1fA, q2fA,
             o1A, o2A, lA1, lA2, kt == qtA, lr, lg, wv, onesf);
    if (kt <= qtB)
      att_step(&K1s[cur][0], &K2s[cur][0], &Vs[cur][0], &Ps[wv][0], q1fB, q2fB,
               o1B, o2B, lB1, lB2, kt == qtB, lr, lg, wv, onesf);
  }
#undef STAGE_KV

#define ATT_EPI(o1_, o2_, l1_, l2_, qt_)                                         \
  do {                                                                           \
    float sum_[4] = {}, sq_[4] = {};                                             \
    float i1_[4], i2_[4];                                                        \
    _Pragma("unroll") for (int r_ = 0; r_ < 4; ++r_) {                           \
      i1_[r_] = 1.f / l1_[r_];                                                   \
      i2_[r_] = lam / l2_[r_];                                                   \
    }                                                                            \
    _Pragma("unroll") for (int nf_ = 0; nf_ < 8; ++nf_)                          \
    _Pragma("unroll") for (int r_ = 0; r_ < 4; ++r_) {                           \
      float v_ = o1_[nf_][r_] * i1_[r_] - o2_[nf_][r_] * i2_[r_];                \
      o1_[nf_][r_] = v_;                                                         \
      sum_[r_] += v_;                                                            \
      sq_[r_] += v_ * v_;                                                        \
    }                                                                            \
    _Pragma("unroll") for (int r_ = 0; r_ < 4; ++r_)                             \
    _Pragma("unroll") for (int mm_ = 8; mm_ >= 1; mm_ >>= 1) {                   \
      sum_[r_] += __shfl_xor(sum_[r_], mm_);                                     \
      sq_[r_] += __shfl_xor(sq_[r_], mm_);                                       \
    }                                                                            \
    _Pragma("unroll") for (int r_ = 0; r_ < 4; ++r_) {                           \
      float mu_ = sum_[r_] * (1.f / 128.f);                                      \
      float var_ = sq_[r_] * (1.f / 128.f) - mu_ * mu_;                          \
      float rs_ = rsqrtf(var_ + 1e-5f) * ONE_MINUS_LI_F;                         \
      int row_ = b * T + (qt_)*64 + wv * 16 + lg * 4 + r_;                       \
      bf16* orow_ = yln + (size_t)row_ * 2048 + h * 128;                         \
      _Pragma("unroll") for (int nf_ = 0; nf_ < 8; ++nf_)                        \
          orow_[nf_ * 16 + lr] = (bf16)((o1_[nf_][r_] - mu_) * rs_);             \
    }                                                                            \
  } while (0)

  ATT_EPI(o1A, o2A, lA1, lA2, qtA);
  ATT_EPI(o1B, o2B, lB1, lB2, qtB);
#undef ATT_EPI
}

// ---------------- launch ----------------

extern "C" void kernel_launch(void* const* d_in, const int* in_sizes, int n_in,
                              void* d_out, int out_size, void* d_ws, size_t ws_size,
                              hipStream_t stream) {
  const float* x   = (const float*)d_in[0];
  const float* q1w = (const float*)d_in[1];
  const float* q2w = (const float*)d_in[2];
  const float* k1w = (const float*)d_in[3];
  const float* k2w = (const float*)d_in[4];
  const float* vw  = (const float*)d_in[5];
  const float* cw  = (const float*)d_in[6];
  const float* lq1 = (const float*)d_in[7];
  const float* lk1 = (const float*)d_in[8];
  const float* lq2 = (const float*)d_in[9];
  const float* lk2 = (const float*)d_in[10];
  float* out = (float*)d_out;

  char* ws = (char*)d_ws;
  bf16* qkv = (bf16*)(ws);                 // 50331648 B
  bf16* Wt  = (bf16*)(ws + 50331648);      // 12582912 B (dead after gemm1)
  bf16* xb  = (bf16*)(ws + 62914560);      // 8388608 B  (dead after gemm1)
  bf16* cwt = (bf16*)(ws + 71303168);      // 4194304 B
  bf16* yln = (bf16*)(ws + 75497472);      // 16777216 B

  const bool fuse_v = (ws_size >= 92274688ull + 16777216ull);
  // fused: Vt after yln (needs 109 MB ws); fallback: Vt overlaps Wt+xb (dead only
  // after gemm1, so fallback uses the separate vtrans kernel)
  bf16* Vt = fuse_v ? (bf16*)(ws + 92274688) : (bf16*)(ws + 50331648);

  cvt_f32_bf16<<<4096, 256, 0, stream>>>(x, xb, 4096 * 1024 / 4);

  transpose_all<<<8192, dim3(32, 8), 0, stream>>>(q1w, q2w, k1w, k2w, vw, cw, Wt, cwt);

  // qkv = x @ [q1|q2|k1|k2|v]; V-part transposed straight into Vt when fused
  if (fuse_v) {
    gemm_bt<bf16, 128, true><<<dim3(48, 32), 256, 0, stream>>>(xb, Wt, qkv, Vt, 4096, 6144, 1024);
  } else {
    gemm_bt<bf16, 128, false><<<dim3(48, 32), 256, 0, stream>>>(xb, Wt, qkv, nullptr, 4096, 6144, 1024);
    vtrans<<<dim3(32, 2, 32), 256, 0, stream>>>(qkv, Vt);
  }

  // differential attention + per-head LN (XCD-locality swizzled 1D grid)
  diff_attn<<<512, 256, 0, stream>>>(qkv, Vt, lq1, lk1, lq2, lk2, yln);

  // out = yln @ c_w
  gemm_bt<float, 64, false><<<dim3(8, 64), 256, 0, stream>>>(yln, cwt, out, nullptr, 4096, 1024, 2048);
}